// Round 1
// baseline (1048.909 us; speedup 1.0000x reference)
//
#include <hip/hip_runtime.h>
#include <math.h>

// Relative-position scaled dot-product attention (fp32 baseline, flash-style).
// B=4 H=16 L=1024 Dh=64; pos table 301x64; mask (B,1,1,L) int, nonzero -> -inf.
//
// Per workgroup (256 threads): one (b,h) and a 16-query tile.
//  - stage q tile [16][64] in LDS (stride 68 to dodge bank conflicts)
//  - precompute bias tile qR[16][301] = q_i . pos_t in LDS
//  - flash loop over 64-wide K/V tiles staged in LDS
//  - online softmax in 16-lane shuffle groups (group g owns query row g)
//  - PV: each lane owns a float4 d-slice; p broadcast via __shfl within group

#define BB 4
#define HH 16
#define LL 1024
#define DHD 64
#define NPOS 301
#define MAXLEN 150
#define QB 16
#define JB 64
#define QS_STRIDE 68
#define KS_STRIDE 68
#define QR_STRIDE 304

__global__ __launch_bounds__(256, 2)
void rp_attn_f32(const float* __restrict__ q,
                 const float* __restrict__ k,
                 const float* __restrict__ v,
                 const float* __restrict__ pos,
                 const int* __restrict__ mask,
                 float* __restrict__ out) {
  __shared__ __attribute__((aligned(16))) float qs[QB * QS_STRIDE];
  __shared__ __attribute__((aligned(16))) float ks[JB * KS_STRIDE];
  __shared__ __attribute__((aligned(16))) float vs[JB * KS_STRIDE];
  __shared__ __attribute__((aligned(16))) float qrs[QB * QR_STRIDE];

  const int tid = threadIdx.x;
  const int bh = blockIdx.y;          // 0..63 : b*16 + h
  const int b  = bh >> 4;
  const int i0 = blockIdx.x * QB;     // query tile base

  const float* qbase = q + (size_t)bh * LL * DHD;
  const float* kbase = k + (size_t)bh * LL * DHD;
  const float* vbase = v + (size_t)bh * LL * DHD;
  const int*   mbase = mask + b * LL;

  // ---- load q tile: 16 rows x 16 float4 = 256 float4, one per thread ----
  {
    int r = tid >> 4;
    int c = (tid & 15) * 4;
    float4 val = *(const float4*)(qbase + (size_t)(i0 + r) * DHD + c);
    *(float4*)(&qs[r * QS_STRIDE + c]) = val;
  }
  __syncthreads();

  // ---- precompute qR[i][t] = q[i,:] . pos[t,:]  (group g handles row i=g) ----
  {
    const int i = tid >> 4;
    const int tsub = tid & 15;
    for (int t = tsub; t < NPOS; t += 16) {
      const float* prow = pos + t * DHD;
      float acc = 0.f;
#pragma unroll
      for (int d4 = 0; d4 < 16; ++d4) {
        float4 pv = *(const float4*)(prow + d4 * 4);
        float4 qv = *(const float4*)(&qs[i * QS_STRIDE + d4 * 4]);
        acc += qv.x * pv.x + qv.y * pv.y + qv.z * pv.z + qv.w * pv.w;
      }
      qrs[i * QR_STRIDE + t] = acc;
    }
  }
  __syncthreads();

  // ---- flash loop ----
  const int i     = tid >> 4;        // query row within tile (16-lane group)
  const int jsub  = tid & 15;        // lane within group
  const int iglob = i0 + i;
  const int d0    = jsub * 4;        // this lane's output d-slice

  float m = -INFINITY;
  float l = 0.f;
  float4 acc = make_float4(0.f, 0.f, 0.f, 0.f);

  for (int j0 = 0; j0 < LL; j0 += JB) {
    __syncthreads();  // previous-iter vs/ks reads done before overwrite
    // stage k,v tiles: 64 rows x 16 float4 each
    for (int t = tid; t < JB * 16; t += 256) {
      int r = t >> 4;
      int c = (t & 15) * 4;
      *(float4*)(&ks[r * KS_STRIDE + c]) =
          *(const float4*)(kbase + (size_t)(j0 + r) * DHD + c);
      *(float4*)(&vs[r * KS_STRIDE + c]) =
          *(const float4*)(vbase + (size_t)(j0 + r) * DHD + c);
    }
    __syncthreads();

    // scores: this lane does j = jsub + 16*s, s = 0..3
    float sc0, sc1, sc2, sc3;
    {
      float d_[4] = {0.f, 0.f, 0.f, 0.f};
#pragma unroll
      for (int s = 0; s < 4; ++s) {
        int j = jsub + 16 * s;
        float dot = 0.f;
#pragma unroll
        for (int d4 = 0; d4 < 16; ++d4) {
          float4 kv4 = *(const float4*)(&ks[j * KS_STRIDE + d4 * 4]);
          float4 qv4 = *(const float4*)(&qs[i * QS_STRIDE + d4 * 4]);
          dot += qv4.x * kv4.x + qv4.y * kv4.y + qv4.z * kv4.z + qv4.w * kv4.w;
        }
        int jg  = j0 + j;
        int rel = jg - iglob;
        // clip(rel,-150,150)+149 ; -1 wraps to row 300
        int idx = (rel <= -MAXLEN) ? (NPOS - 1)
                : (rel >=  MAXLEN) ? (NPOS - 2)
                                   : (rel + MAXLEN - 1);
        dot += qrs[i * QR_STRIDE + idx];
        dot *= 0.125f;                       // / sqrt(64)
        if (mbase[jg] != 0) dot = -INFINITY; // mask True -> -inf
        d_[s] = dot;
      }
      sc0 = d_[0]; sc1 = d_[1]; sc2 = d_[2]; sc3 = d_[3];
    }

    // group-wide row max
    float tmax = fmaxf(fmaxf(sc0, sc1), fmaxf(sc2, sc3));
#pragma unroll
    for (int off = 1; off < 16; off <<= 1)
      tmax = fmaxf(tmax, __shfl_xor(tmax, off, 16));

    float m_new = fmaxf(m, tmax);
    float alpha, p0, p1, p2, p3;
    if (m_new == -INFINITY) {      // whole-tile masked so far: no-op update
      alpha = 1.f; p0 = p1 = p2 = p3 = 0.f;
    } else {
      alpha = __expf(m - m_new);   // m==-inf -> 0
      p0 = __expf(sc0 - m_new);
      p1 = __expf(sc1 - m_new);
      p2 = __expf(sc2 - m_new);
      p3 = __expf(sc3 - m_new);
    }
    m = m_new;

    float psum = p0 + p1 + p2 + p3;
#pragma unroll
    for (int off = 1; off < 16; off <<= 1)
      psum += __shfl_xor(psum, off, 16);
    l = l * alpha + psum;

    acc.x *= alpha; acc.y *= alpha; acc.z *= alpha; acc.w *= alpha;

    // PV: broadcast each source lane's 4 p values to the group
#pragma unroll
    for (int jj = 0; jj < 16; ++jj) {
      float q0 = __shfl(p0, jj, 16);
      float q1 = __shfl(p1, jj, 16);
      float q2 = __shfl(p2, jj, 16);
      float q3 = __shfl(p3, jj, 16);
      float4 v0 = *(const float4*)(&vs[(jj     ) * KS_STRIDE + d0]);
      float4 v1 = *(const float4*)(&vs[(jj + 16) * KS_STRIDE + d0]);
      float4 v2 = *(const float4*)(&vs[(jj + 32) * KS_STRIDE + d0]);
      float4 v3 = *(const float4*)(&vs[(jj + 48) * KS_STRIDE + d0]);
      acc.x += q0 * v0.x + q1 * v1.x + q2 * v2.x + q3 * v3.x;
      acc.y += q0 * v0.y + q1 * v1.y + q2 * v2.y + q3 * v3.y;
      acc.z += q0 * v0.z + q1 * v1.z + q2 * v2.z + q3 * v3.z;
      acc.w += q0 * v0.w + q1 * v1.w + q2 * v2.w + q3 * v3.w;
    }
  }

  const float inv_l = 1.f / l;
  float4 o;
  o.x = acc.x * inv_l;
  o.y = acc.y * inv_l;
  o.z = acc.z * inv_l;
  o.w = acc.w * inv_l;
  *(float4*)(out + ((size_t)bh * LL + iglob) * DHD + d0) = o;
}

extern "C" void kernel_launch(void* const* d_in, const int* in_sizes, int n_in,
                              void* d_out, int out_size, void* d_ws, size_t ws_size,
                              hipStream_t stream) {
  const float* q   = (const float*)d_in[0];
  const float* k   = (const float*)d_in[1];
  const float* v   = (const float*)d_in[2];
  const float* pos = (const float*)d_in[3];
  const int*   msk = (const int*)d_in[4];
  float* out = (float*)d_out;

  dim3 grid(LL / QB, BB * HH);   // (64 query tiles, 64 bh)
  dim3 block(256);
  rp_attn_f32<<<grid, block, 0, stream>>>(q, k, v, pos, msk, out);
}

// Round 2
// 134.350 us; speedup vs baseline: 7.8073x; 7.8073x over previous
//
#include <hip/hip_runtime.h>
#include <math.h>

// RP scaled-dot-product attention, bf16-MFMA flash kernel.
// B=4 H=16 L=1024 Dh=64. One WG (256 thr, 4 waves) per (bh, 64-query tile).
// - Q A-frags in registers; bias table qR = Q.pos^T via MFMA into LDS (bf16)
// - K staged bf16 [64][64] XOR-swizzled; V staged transposed [d][k] swizzled
// - S = Q.K^T via 16x16x32 MFMA; bias gather + scale + mask in f32
// - online softmax in 16-lane shfl groups; P -> LDS (bf16) -> A-frags; PV MFMA
//
// MFMA 16x16x32 layouts used (guide §3, m89-verified):
//   A: lane l holds A[l&15][(l>>4)*8+j]   B: lane l holds B[(l>>4)*8+j][l&15]
//   C: lane l, reg r holds C[(l>>4)*4+r][l&15]

#define LL 1024
#define DH 64
#define NPOS 301
#define MAXL 150
#define QT 64
#define QRS_B 616   // qrs row stride in bytes (308 bf16 slots, bank-staggered)

typedef __attribute__((ext_vector_type(8))) short short8;
typedef __attribute__((ext_vector_type(4))) float f32x4;

__device__ __forceinline__ unsigned short f2bf(float f) {
  unsigned u = __float_as_uint(f);
  u += 0x7FFFu + ((u >> 16) & 1u);   // RNE (no NaN in data)
  return (unsigned short)(u >> 16);
}
__device__ __forceinline__ float bf2f(unsigned short s) {
  return __uint_as_float((unsigned)s << 16);
}
__device__ __forceinline__ short8 pack8(float4 a, float4 b) {
  short8 r;
  r[0] = (short)f2bf(a.x); r[1] = (short)f2bf(a.y);
  r[2] = (short)f2bf(a.z); r[3] = (short)f2bf(a.w);
  r[4] = (short)f2bf(b.x); r[5] = (short)f2bf(b.y);
  r[6] = (short)f2bf(b.z); r[7] = (short)f2bf(b.w);
  return r;
}
// byte offset in a 128B-row LDS tile, XOR-swizzled (G4 fix for D=64 bf16 rows)
__device__ __forceinline__ int swz(int row, int byte_in_row) {
  return row * 128 + (byte_in_row ^ ((row & 7) << 4));
}

__global__ __launch_bounds__(256, 2)
void rp_attn_mfma(const float* __restrict__ Q, const float* __restrict__ K,
                  const float* __restrict__ V, const float* __restrict__ POS,
                  const int* __restrict__ MSK, float* __restrict__ OUT) {
  __shared__ __attribute__((aligned(16))) unsigned char qrs[64 * QRS_B]; // 39424 B
  __shared__ __attribute__((aligned(16))) unsigned char ks[64 * 128];    // 8192 B
  __shared__ __attribute__((aligned(16))) unsigned char vt[64 * 128];    // 8192 B
  __shared__ __attribute__((aligned(16))) unsigned char pb[4 * 16 * 128];// 8192 B

  const int tid = threadIdx.x;
  // XCD-chunked block swizzle: XCD d serves bh in [8d, 8d+8) -> K/V fits its L2
  const int F   = blockIdx.x;
  const int gi  = F >> 3;
  const int bh  = (F & 7) * 8 + (gi >> 4);
  const int i0  = (gi & 15) * QT;
  const int b   = bh >> 4;

  const int wq = tid >> 6;    // wave 0..3 -> q rows [wq*16, wq*16+16)
  const int l  = tid & 63;
  const int g  = l >> 4;
  const int c  = l & 15;

  const size_t bhoff = (size_t)bh * LL * DH;
  const float* qp = Q + bhoff;
  const float* kp = K + bhoff;
  const float* vp = V + bhoff;
  const int*   mrow = MSK + b * LL;

  // ---- Q A-frags (held in registers for the whole kernel) ----
  short8 qA0, qA1;
  {
    const float* qr = qp + (size_t)(i0 + wq * 16 + c) * DH;
    float4 a  = *(const float4*)(qr + 8 * g);
    float4 bq = *(const float4*)(qr + 8 * g + 4);
    qA0 = pack8(a, bq);
    a  = *(const float4*)(qr + 32 + 8 * g);
    bq = *(const float4*)(qr + 32 + 8 * g + 4);
    qA1 = pack8(a, bq);
  }

  // ---- qR[q][t] = Q . pos^T via MFMA (each wave its own 16 q rows) ----
  unsigned char* qrow_base = qrs + (wq * 16) * QRS_B;
  for (int nt = 0; nt < 19; ++nt) {
    int t  = 16 * nt + c;
    int tc = t > 300 ? 300 : t;           // clamp: cols 301..303 junk, never read
    const float* pr = POS + (size_t)tc * DH;
    float4 a  = *(const float4*)(pr + 8 * g);
    float4 bq = *(const float4*)(pr + 8 * g + 4);
    short8 B0 = pack8(a, bq);
    a  = *(const float4*)(pr + 32 + 8 * g);
    bq = *(const float4*)(pr + 32 + 8 * g + 4);
    short8 B1 = pack8(a, bq);
    f32x4 gacc = {0.f, 0.f, 0.f, 0.f};
    gacc = __builtin_amdgcn_mfma_f32_16x16x32_bf16(qA0, B0, gacc, 0, 0, 0);
    gacc = __builtin_amdgcn_mfma_f32_16x16x32_bf16(qA1, B1, gacc, 0, 0, 0);
#pragma unroll
    for (int r = 0; r < 4; ++r)
      *(unsigned short*)(qrow_base + (4 * g + r) * QRS_B + t * 2) = f2bf(gacc[r]);
  }

  float mrun[4], lrun[4];
  f32x4 acc[4];
  f32x4 fzero = {0.f, 0.f, 0.f, 0.f};
#pragma unroll
  for (int r = 0; r < 4; ++r) { mrun[r] = -INFINITY; lrun[r] = 0.f; }
#pragma unroll
  for (int dt = 0; dt < 4; ++dt) acc[dt] = fzero;

  unsigned char* pwave = pb + wq * (16 * 128);

  for (int tl = 0; tl < 16; ++tl) {
    const int j0 = tl * 64;
    __syncthreads();                       // prior tile's ks/vt reads complete
    // stage K tile -> bf16 swizzled
    {
      int kk = tid >> 2, c0 = (tid & 3) * 16;
      const float* src = kp + (size_t)(j0 + kk) * DH + c0;
      float4 a  = *(const float4*)(src);
      float4 bq = *(const float4*)(src + 4);
      float4 cc = *(const float4*)(src + 8);
      float4 dd = *(const float4*)(src + 12);
      *(short8*)(ks + swz(kk, c0 * 2))      = pack8(a, bq);
      *(short8*)(ks + swz(kk, c0 * 2 + 16)) = pack8(cc, dd);
    }
    // stage V transposed -> vt[d][k], bf16 swizzled
    {
      int kk = tid & 63, d0 = (tid >> 6) * 16;
      const float* src = vp + (size_t)(j0 + kk) * DH + d0;
      float4 va = *(const float4*)(src);
      float4 vb = *(const float4*)(src + 4);
      float4 vc = *(const float4*)(src + 8);
      float4 vd = *(const float4*)(src + 12);
      float vals[16] = {va.x, va.y, va.z, va.w, vb.x, vb.y, vb.z, vb.w,
                        vc.x, vc.y, vc.z, vc.w, vd.x, vd.y, vd.z, vd.w};
#pragma unroll
      for (int i = 0; i < 16; ++i)
        *(unsigned short*)(vt + swz(d0 + i, kk * 2)) = f2bf(vals[i]);
    }
    __syncthreads();

    // ---- S = Q.K^T ----
    f32x4 s[4];
#pragma unroll
    for (int nt = 0; nt < 4; ++nt) {
      f32x4 z = fzero;
      short8 kb0 = *(short8*)(ks + swz(16 * nt + c, 16 * g));
      short8 kb1 = *(short8*)(ks + swz(16 * nt + c, 64 + 16 * g));
      z = __builtin_amdgcn_mfma_f32_16x16x32_bf16(qA0, kb0, z, 0, 0, 0);
      z = __builtin_amdgcn_mfma_f32_16x16x32_bf16(qA1, kb1, z, 0, 0, 0);
      s[nt] = z;
    }

    // ---- bias gather + scale + mask ----
#pragma unroll
    for (int nt = 0; nt < 4; ++nt) {
      int jg = j0 + 16 * nt + c;
      float mb = mrow[jg] ? -INFINITY : 0.0f;
#pragma unroll
      for (int r = 0; r < 4; ++r) {
        int ig  = i0 + wq * 16 + 4 * g + r;
        int rel = jg - ig;
        int idx = rel <= -MAXL ? 300 : (rel >= MAXL ? 299 : rel + MAXL - 1);
        float bias = bf2f(*(const unsigned short*)(qrow_base + (4 * g + r) * QRS_B + idx * 2));
        s[nt][r] = (s[nt][r] + bias) * 0.125f + mb;
      }
    }

    // ---- online softmax (per q-row r, reduced across the 16-lane group) ----
    float mt[4];
#pragma unroll
    for (int r = 0; r < 4; ++r) {
      float v0 = fmaxf(fmaxf(s[0][r], s[1][r]), fmaxf(s[2][r], s[3][r]));
#pragma unroll
      for (int o = 1; o < 16; o <<= 1) v0 = fmaxf(v0, __shfl_xor(v0, o, 16));
      mt[r] = v0;
    }
    float alpha[4];
#pragma unroll
    for (int r = 0; r < 4; ++r) {
      float mn = fmaxf(mrun[r], mt[r]);
      alpha[r] = (mn == -INFINITY) ? 1.f : __expf(mrun[r] - mn);
      mrun[r]  = mn;
    }
#pragma unroll
    for (int nt = 0; nt < 4; ++nt)
#pragma unroll
      for (int r = 0; r < 4; ++r)
        s[nt][r] = (mrun[r] == -INFINITY) ? 0.f : __expf(s[nt][r] - mrun[r]);
#pragma unroll
    for (int r = 0; r < 4; ++r) {
      float ls = s[0][r] + s[1][r] + s[2][r] + s[3][r];
#pragma unroll
      for (int o = 1; o < 16; o <<= 1) ls += __shfl_xor(ls, o, 16);
      lrun[r] = lrun[r] * alpha[r] + ls;
    }
#pragma unroll
    for (int dt = 0; dt < 4; ++dt)
#pragma unroll
      for (int r = 0; r < 4; ++r) acc[dt][r] *= alpha[r];

    // ---- P -> LDS (bf16, swizzled) -> A-frags ----
#pragma unroll
    for (int nt = 0; nt < 4; ++nt)
#pragma unroll
      for (int r = 0; r < 4; ++r)
        *(unsigned short*)(pwave + swz(4 * g + r, (16 * nt + c) * 2)) = f2bf(s[nt][r]);

    short8 pa0 = *(short8*)(pwave + swz(c, 16 * g));
    short8 pa1 = *(short8*)(pwave + swz(c, 64 + 16 * g));

    // ---- PV ----
#pragma unroll
    for (int dt = 0; dt < 4; ++dt) {
      short8 vb0 = *(short8*)(vt + swz(16 * dt + c, 16 * g));
      short8 vb1 = *(short8*)(vt + swz(16 * dt + c, 64 + 16 * g));
      acc[dt] = __builtin_amdgcn_mfma_f32_16x16x32_bf16(pa0, vb0, acc[dt], 0, 0, 0);
      acc[dt] = __builtin_amdgcn_mfma_f32_16x16x32_bf16(pa1, vb1, acc[dt], 0, 0, 0);
    }
  }

  // ---- epilogue ----
  float inv[4];
#pragma unroll
  for (int r = 0; r < 4; ++r) inv[r] = 1.f / lrun[r];
  float* orow = OUT + bhoff + (size_t)(i0 + wq * 16) * DH;
#pragma unroll
  for (int dt = 0; dt < 4; ++dt)
#pragma unroll
    for (int r = 0; r < 4; ++r)
      orow[(4 * g + r) * DH + 16 * dt + c] = acc[dt][r] * inv[r];
}

extern "C" void kernel_launch(void* const* d_in, const int* in_sizes, int n_in,
                              void* d_out, int out_size, void* d_ws, size_t ws_size,
                              hipStream_t stream) {
  const float* q   = (const float*)d_in[0];
  const float* k   = (const float*)d_in[1];
  const float* v   = (const float*)d_in[2];
  const float* pos = (const float*)d_in[3];
  const int*   msk = (const int*)d_in[4];
  float* out = (float*)d_out;

  rp_attn_mfma<<<dim3(1024), dim3(256), 0, stream>>>(q, k, v, pos, msk, out);
}

// Round 5
// 98.667 us; speedup vs baseline: 10.6308x; 1.3617x over previous
//
#include <hip/hip_runtime.h>
#include <math.h>

// RP scaled-dot-product attention, swapped-QK^T 32x32x16 MFMA flash kernel.
// B=4 H=16 L=1024 Dh=64.  One WG (256 thr, 4 waves) per (bh, 64-query tile).
// Waves: (qgroup 0/1) x (k-half 0/1); flash-merge of k-halves at the end.
//
// BISECTION ROUND: rounds 3/4 failed identically (absmax ~1.05) with the only
// unverified pieces being v_cvt_pk_bf16_f32 asm and permlane32_swap. This
// round replaces BOTH with session-verified mechanisms:
//   - bf16 packing via pure-VALU f2bf (round-2-verified RNE)
//   - cross-lane +-32 exchange via __shfl_xor(.,32) + per-lane select
// Everything else is identical to round 4.
//
// 32x32x16 bf16 layouts (C verified m74/m101):
//   A: lane l holds A[l&31][(l>>5)*8+j]   B: lane l holds B[(l>>5)*8+j][l&31]
//   C: lane l reg r holds C[(r&3)+8*(r>>2)+4*(l>>5)][l&31]
// (A/B intra-frag k-order cancels: both operands of every MFMA here are built
//  with the same mapping and k is contracted.)

#define LL 1024
#define DH 64
#define MAXL 150

typedef __attribute__((ext_vector_type(8)))  short    short8;
typedef __attribute__((ext_vector_type(4)))  float    f32x4;
typedef __attribute__((ext_vector_type(16))) float    f32x16;
typedef __attribute__((ext_vector_type(4)))  unsigned u32x4;

union U4S8 { u32x4 u; short8 s; };

__device__ __forceinline__ unsigned f2bf(float f) {
  unsigned u = __float_as_uint(f);
  u += 0x7FFFu + ((u >> 16) & 1u);   // RNE (no NaN in converted data)
  return u >> 16;
}
__device__ __forceinline__ unsigned pkbf(float lo, float hi) {
  return f2bf(lo) | (f2bf(hi) << 16);
}
__device__ __forceinline__ float bf2f(unsigned short s) {
  return __uint_as_float((unsigned)s << 16);
}
__device__ __forceinline__ short8 pack8f(float4 a, float4 b) {
  U4S8 t;
  t.u[0] = pkbf(a.x, a.y); t.u[1] = pkbf(a.z, a.w);
  t.u[2] = pkbf(b.x, b.y); t.u[3] = pkbf(b.z, b.w);
  return t.s;
}
// byte offset in a 128B-row LDS tile, XOR-swizzled (G4)
__device__ __forceinline__ int swz(int row, int cb) {
  return row * 128 + (cb ^ ((row & 7) << 4));
}
__device__ __forceinline__ void st_pair(unsigned char* base, int row, int colb,
                                        float a, float b) {
  unsigned u = pkbf(a, b);
  *(unsigned short*)(base + swz(row, colb))     = (unsigned short)u;
  *(unsigned short*)(base + swz(row + 1, colb)) = (unsigned short)(u >> 16);
}
#define KOFF(r) ((((r) & 3)) + 8 * ((r) >> 2))

__global__ __launch_bounds__(256, 2)
void rp_attn32(const float* __restrict__ Q, const float* __restrict__ K,
               const float* __restrict__ V, const float* __restrict__ POS,
               const int* __restrict__ MSK, float* __restrict__ OUT) {
  // qrs: bias table, row stride 306 u16 = 612 B (odd dword stride)
  __shared__ __attribute__((aligned(16))) unsigned short qrs[64][306]; // 39168 B
  __shared__ __attribute__((aligned(16))) unsigned char  kv[32768];    // K h0,h1 | V^T h0,h1
  __shared__ __attribute__((aligned(16))) float          mskf[2][64];  // 512 B

  const int tid = threadIdx.x;
  // XCD-chunked swizzle: XCD d serves bh in [8d,8d+8) -> K/V fits its 4MB L2
  const int F  = blockIdx.x;
  const int gi = F >> 3;
  const int bh = (F & 7) * 8 + (gi >> 4);
  const int i0 = (gi & 15) * 64;
  const int b  = bh >> 4;

  const int wave = tid >> 6, lane = tid & 63;
  const int lo5 = lane & 31, hi = lane >> 5;
  const int qg = wave & 1, kh = wave >> 1;   // q-group, k-half
  const int qloc = qg * 32 + lo5;
  const int irow = i0 + qloc;

  const size_t bo = (size_t)bh * LL * DH;
  const float* qp = Q + bo;
  const float* kp = K + bo;
  const float* vp = V + bo;
  const int*   mrow = MSK + b * LL;

  unsigned char* ksh = kv + kh * 8192;           // this wave's K half-tile
  unsigned char* vth = kv + 16384 + kh * 8192;   // this wave's V^T half-tile

  // ---- Q^T B-frags, held in registers: qB[c] covers d = c*16 + hi*8 + j ----
  short8 qB[4];
#pragma unroll
  for (int c = 0; c < 4; ++c) {
    const float* src = qp + (size_t)irow * DH + c * 16 + hi * 8;
    qB[c] = pack8f(*(const float4*)src, *(const float4*)(src + 4));
  }

  // ---- bias table: qR^T = pos . Q^T via MFMA; this wave: its qg rows,
  //      t-blocks tb = kh, kh+2, ... (5 of 10) ----
  for (int tb = kh; tb < 10; tb += 2) {
    int trow = tb * 32 + lo5; if (trow > 300) trow = 300;
    const float* pr = POS + (size_t)trow * DH;
    f32x16 z;
#pragma unroll
    for (int x = 0; x < 16; ++x) z[x] = 0.f;
#pragma unroll
    for (int c = 0; c < 4; ++c) {
      const float* s2 = pr + c * 16 + hi * 8;
      short8 af = pack8f(*(const float4*)s2, *(const float4*)(s2 + 4));
      z = __builtin_amdgcn_mfma_f32_32x32x16_bf16(af, qB[c], z, 0, 0, 0);
    }
#pragma unroll
    for (int rp = 0; rp < 8; ++rp) {
      const int r = rp * 2;
      int tp = KOFF(r) + 4 * hi + 32 * tb;
      if (tp < 306)  // keep junk cols inside the row (t<=300 ever read)
        *(unsigned*)(&qrs[qloc][tp]) = pkbf(z[r], z[r + 1]);
    }
  }

  // ---- flash state (base-2 domain) ----
  const float SC = 0.18033688011112042f;  // 0.125 * log2(e)
  float m2 = -1e30f, lsum = 0.f;
  f32x16 acc0, acc1;
#pragma unroll
  for (int x = 0; x < 16; ++x) { acc0[x] = 0.f; acc1[x] = 0.f; }

  for (int rd = 0; rd < 8; ++rd) {
    __syncthreads();  // prior round's ks/vt reads complete (covers table @rd=0)
    // ---- stage K + V^T (both halves) + mask, bf16 swizzled ----
    {
      const int r = tid >> 2, q4 = tid & 3, r2 = r * 2, rb = q4 * 16;
#pragma unroll
      for (int h = 0; h < 2; ++h) {
        const int j0h = h * 512 + rd * 64;
        const float* ksrc = kp + (size_t)(j0h + r) * DH + q4 * 16;
        float4 k0 = ((const float4*)ksrc)[0], k1 = ((const float4*)ksrc)[1];
        float4 k2 = ((const float4*)ksrc)[2], k3 = ((const float4*)ksrc)[3];
        unsigned char* kb_ = kv + h * 8192;
        *(short8*)(kb_ + swz(r, q4 * 32))      = pack8f(k0, k1);
        *(short8*)(kb_ + swz(r, q4 * 32 + 16)) = pack8f(k2, k3);
        const float* vsrc = vp + (size_t)(j0h + r) * DH + q4 * 16;
        float4 v0 = ((const float4*)vsrc)[0], v1 = ((const float4*)vsrc)[1];
        float4 v2 = ((const float4*)vsrc)[2], v3 = ((const float4*)vsrc)[3];
        unsigned char* vb_ = kv + 16384 + h * 8192;
        st_pair(vb_, rb + 0,  r2, v0.x, v0.y); st_pair(vb_, rb + 2,  r2, v0.z, v0.w);
        st_pair(vb_, rb + 4,  r2, v1.x, v1.y); st_pair(vb_, rb + 6,  r2, v1.z, v1.w);
        st_pair(vb_, rb + 8,  r2, v2.x, v2.y); st_pair(vb_, rb + 10, r2, v2.z, v2.w);
        st_pair(vb_, rb + 12, r2, v3.x, v3.y); st_pair(vb_, rb + 14, r2, v3.z, v3.w);
      }
      if (tid < 128) {
        int h = tid >> 6, kk = tid & 63;
        mskf[h][kk] = mrow[h * 512 + rd * 64 + kk] ? -INFINITY : 0.0f;
      }
    }
    __syncthreads();

    const int j0 = kh * 512 + rd * 64;

    // ---- S^T = K . Q^T ----
    f32x16 st[2];
#pragma unroll
    for (int kb = 0; kb < 2; ++kb) {
      f32x16 z;
#pragma unroll
      for (int x = 0; x < 16; ++x) z[x] = 0.f;
#pragma unroll
      for (int c = 0; c < 4; ++c) {
        short8 kf = *(const short8*)(ksh + swz(kb * 32 + lo5, c * 32 + hi * 16));
        z = __builtin_amdgcn_mfma_f32_32x32x16_bf16(kf, qB[c], z, 0, 0, 0);
      }
      st[kb] = z;
    }

    // ---- bias gather + scale + mask (lane owns q-row irow; k varies by reg) ----
#pragma unroll
    for (int kb = 0; kb < 2; ++kb) {
      const int jb = j0 + kb * 32;
      f32x4 mg[4];
#pragma unroll
      for (int g4 = 0; g4 < 4; ++g4)
        mg[g4] = *(const f32x4*)&mskf[kh][kb * 32 + g4 * 8 + 4 * hi];
      const int relmin = jb - (i0 + qg * 32 + 31);
      const int relmax = jb + 31 - (i0 + qg * 32);
      if (relmin >= MAXL) {           // whole block saturates high -> idx 299
        const float bias = bf2f(qrs[qloc][299]);
#pragma unroll
        for (int r = 0; r < 16; ++r)
          st[kb][r] = (st[kb][r] + bias) * SC + mg[r >> 2][r & 3];
      } else if (relmax <= -MAXL) {   // saturates low -> wrap row 300
        const float bias = bf2f(qrs[qloc][300]);
#pragma unroll
        for (int r = 0; r < 16; ++r)
          st[kb][r] = (st[kb][r] + bias) * SC + mg[r >> 2][r & 3];
      } else {                        // near-diagonal: per-element gather
#pragma unroll
        for (int r = 0; r < 16; ++r) {
          const int rel = jb + KOFF(r) + 4 * hi - irow;
          const int idx = rel <= -MAXL ? 300 : (rel >= MAXL ? 299 : rel + MAXL - 1);
          st[kb][r] = (st[kb][r] + bf2f(qrs[qloc][idx])) * SC + mg[r >> 2][r & 3];
        }
      }
    }

    // ---- online softmax (in-lane tree + partner-lane combine) ----
    f32x16 mx;
#pragma unroll
    for (int r = 0; r < 16; ++r) mx[r] = fmaxf(st[0][r], st[1][r]);
#pragma unroll
    for (int w = 8; w > 0; w >>= 1)
#pragma unroll
      for (int r = 0; r < 8; ++r)
        if (r < w) mx[r] = fmaxf(mx[r], mx[r + w]);
    float tmax = fmaxf(mx[0], __shfl_xor(mx[0], 32));
    const float mnew = fmaxf(m2, tmax);      // >= -1e30 always (no -inf/NaN)
    const float alpha = exp2f(m2 - mnew);
#pragma unroll
    for (int kb = 0; kb < 2; ++kb)
#pragma unroll
      for (int r = 0; r < 16; ++r) st[kb][r] = exp2f(st[kb][r] - mnew);
    f32x16 sx;
#pragma unroll
    for (int r = 0; r < 16; ++r) sx[r] = st[0][r] + st[1][r];
#pragma unroll
    for (int w = 8; w > 0; w >>= 1)
#pragma unroll
      for (int r = 0; r < 8; ++r)
        if (r < w) sx[r] = sx[r] + sx[r + w];
    const float ps = sx[0] + __shfl_xor(sx[0], 32);
    lsum = lsum * alpha + ps;
    m2 = mnew;
    acc0 *= alpha; acc1 *= alpha;

    // ---- P^T frags in-register: pack pairs, exchange +-32 via shfl_xor ----
    // Lane (hi,lo5) needs B[k=hi*8+j][q=lo5], k within 16-block ch.
    //   own regs give k-pairs (4hi+0,1),(4hi+2,3),(8+4hi+0,1),(8+4hi+2,3);
    //   partner lane (hi^1) supplies the other four pairs.
    short8 pf[4];
#pragma unroll
    for (int ch = 0; ch < 4; ++ch) {
      const int kb = ch >> 1, rb2 = (ch & 1) * 8;
      unsigned a  = pkbf(st[kb][rb2 + 0], st[kb][rb2 + 1]);
      unsigned a2 = pkbf(st[kb][rb2 + 2], st[kb][rb2 + 3]);
      unsigned bb = pkbf(st[kb][rb2 + 4], st[kb][rb2 + 5]);
      unsigned b2 = pkbf(st[kb][rb2 + 6], st[kb][rb2 + 7]);
      unsigned sa  = __shfl_xor(a, 32);
      unsigned sa2 = __shfl_xor(a2, 32);
      unsigned sbb = __shfl_xor(bb, 32);
      unsigned sb2 = __shfl_xor(b2, 32);
      U4S8 t;
      t.u[0] = hi ? sbb : a;    // k(0,1)  | k(8,9)
      t.u[1] = hi ? sb2 : a2;   // k(2,3)  | k(10,11)
      t.u[2] = hi ? bb  : sa;   // k(4,5)  | k(12,13)
      t.u[3] = hi ? b2  : sa2;  // k(6,7)  | k(14,15)
      pf[ch] = t.s;
    }

    // ---- PV: O^T += V^T . P^T ----
#pragma unroll
    for (int ch = 0; ch < 4; ++ch) {
      short8 vf0 = *(const short8*)(vth + swz(lo5,      ch * 32 + hi * 16));
      short8 vf1 = *(const short8*)(vth + swz(32 + lo5, ch * 32 + hi * 16));
      acc0 = __builtin_amdgcn_mfma_f32_32x32x16_bf16(vf0, pf[ch], acc0, 0, 0, 0);
      acc1 = __builtin_amdgcn_mfma_f32_32x32x16_bf16(vf1, pf[ch], acc1, 0, 0, 0);
    }
  }

  // ---- k-half merge (flash combine) + epilogue ----
  __syncthreads();
  float* mb = (float*)kv;  // reuse K/V LDS: 128 lanes * 37 f32 = 18944 B
  if (wave >= 2) {
    float* d = mb + ((wave - 2) * 64 + lane) * 37;
    d[0] = m2; d[1] = lsum;
#pragma unroll
    for (int r = 0; r < 16; ++r) { d[2 + r] = acc0[r]; d[18 + r] = acc1[r]; }
  }
  __syncthreads();
  if (wave < 2) {
    const float* d = mb + (wave * 64 + lane) * 37;
    const float m1 = d[0], l1 = d[1];
    const float mf = fmaxf(m2, m1);
    const float a0 = exp2f(m2 - mf), a1 = exp2f(m1 - mf);
    const float lf = lsum * a0 + l1 * a1;
    const float inv = 1.f / lf;
    float* op = OUT + bo + (size_t)irow * DH;
#pragma unroll
    for (int r = 0; r < 16; ++r) {
      const int d0 = KOFF(r) + 4 * hi;
      op[d0]      = (acc0[r] * a0 + d[2 + r]  * a1) * inv;
      op[d0 + 32] = (acc1[r] * a0 + d[18 + r] * a1) * inv;
    }
  }
}

extern "C" void kernel_launch(void* const* d_in, const int* in_sizes, int n_in,
                              void* d_out, int out_size, void* d_ws, size_t ws_size,
                              hipStream_t stream) {
  const float* q   = (const float*)d_in[0];
  const float* k   = (const float*)d_in[1];
  const float* v   = (const float*)d_in[2];
  const float* pos = (const float*)d_in[3];
  const int*   msk = (const int*)d_in[4];
  float* out = (float*)d_out;

  rp_attn32<<<dim3(1024), dim3(256), 0, stream>>>(q, k, v, pos, msk, out);
}

// Round 6
// 95.128 us; speedup vs baseline: 11.0263x; 1.0372x over previous
//
#include <hip/hip_runtime.h>
#include <math.h>

// RP scaled-dot-product attention, swapped-QK^T 32x32x16 MFMA flash kernel.
// B=4 H=16 L=1024 Dh=64.  One WG (256 thr, 4 waves) per (bh, 64-query tile).
// Waves: (qgroup 0/1) x (k-half 0/1); flash-merge of k-halves at the end.
//
// Round 6 = round 5 (verified) +
//   (1) v_cvt_pk_bf16_f32 for ALL bf16 packing (1 op vs ~7); P-exchange stays
//       on round-5-verified __shfl_xor (permlane stays out).
//   (2) V^T staging back to round-2's conflict-free mapping (col spans 128B).
//   (3) T14 async-stage: next tile's K/V global loads issued before compute.
//   (4) T13 defer-max (THR=12 base-2) + mask pre-staged to LDS once.
//
// 32x32x16 bf16 layouts (C verified m74/m101):
//   A: lane l holds A[l&31][(l>>5)*8+j]   B: lane l holds B[(l>>5)*8+j][l&31]
//   C: lane l reg r holds C[(r&3)+8*(r>>2)+4*(l>>5)][l&31]

#define LL 1024
#define DH 64
#define MAXL 150

typedef __attribute__((ext_vector_type(8)))  short    short8;
typedef __attribute__((ext_vector_type(4)))  float    f32x4;
typedef __attribute__((ext_vector_type(16))) float    f32x16;
typedef __attribute__((ext_vector_type(4)))  unsigned u32x4;

union U4S8 { u32x4 u; short8 s; };

__device__ __forceinline__ unsigned cvtpk(float lo, float hi) {
  unsigned r;
  asm("v_cvt_pk_bf16_f32 %0, %1, %2" : "=v"(r) : "v"(lo), "v"(hi));
  return r;
}
__device__ __forceinline__ float bf2f(unsigned short s) {
  return __uint_as_float((unsigned)s << 16);
}
__device__ __forceinline__ short8 pack8f(float4 a, float4 b) {
  U4S8 t;
  t.u[0] = cvtpk(a.x, a.y); t.u[1] = cvtpk(a.z, a.w);
  t.u[2] = cvtpk(b.x, b.y); t.u[3] = cvtpk(b.z, b.w);
  return t.s;
}
// byte offset in a 128B-row LDS tile, XOR-swizzled (G4)
__device__ __forceinline__ int swz(int row, int cb) {
  return row * 128 + (cb ^ ((row & 7) << 4));
}
__device__ __forceinline__ void st_pair(unsigned char* base, int row, int colb,
                                        float a, float b) {
  unsigned u = cvtpk(a, b);
  *(unsigned short*)(base + swz(row, colb))     = (unsigned short)u;
  *(unsigned short*)(base + swz(row + 1, colb)) = (unsigned short)(u >> 16);
}
#define KOFF(r) ((((r) & 3)) + 8 * ((r) >> 2))

__global__ __launch_bounds__(256, 2)
void rp_attn32(const float* __restrict__ Q, const float* __restrict__ K,
               const float* __restrict__ V, const float* __restrict__ POS,
               const int* __restrict__ MSK, float* __restrict__ OUT) {
  // qrs: bias table, row stride 306 u16 = 612 B (odd dword stride)
  __shared__ __attribute__((aligned(16))) unsigned short qrs[64][306]; // 39168 B
  __shared__ __attribute__((aligned(16))) unsigned char  kv[32768];    // K h0,h1 | V^T h0,h1
  __shared__ __attribute__((aligned(16))) float          mskf[1024];   // 4096 B

  const int tid = threadIdx.x;
  // XCD-chunked swizzle: XCD d serves bh in [8d,8d+8) -> K/V fits its 4MB L2
  const int F  = blockIdx.x;
  const int gi = F >> 3;
  const int bh = (F & 7) * 8 + (gi >> 4);
  const int i0 = (gi & 15) * 64;
  const int b  = bh >> 4;

  const int wave = tid >> 6, lane = tid & 63;
  const int lo5 = lane & 31, hi = lane >> 5;
  const int qg = wave & 1, kh = wave >> 1;   // q-group, k-half
  const int qloc = qg * 32 + lo5;
  const int irow = i0 + qloc;

  // staging thread mappings
  const int rK = tid >> 2, q4 = tid & 3;     // K: row rK, d-slice q4*16
  const int kkV = tid & 63, dwV = wave;      // V: row kkV, d-slice wave*16

  const size_t bo = (size_t)bh * LL * DH;
  const float* qp = Q + bo;
  const float* kp = K + bo;
  const float* vp = V + bo;
  const int*   mrow = MSK + b * LL;

  unsigned char* ksh = kv + kh * 8192;           // this wave's K half-tile
  unsigned char* vth = kv + 16384 + kh * 8192;   // this wave's V^T half-tile

  // ---- Q^T B-frags, held in registers: qB[c] covers d = c*16 + hi*8 + j ----
  short8 qB[4];
#pragma unroll
  for (int c = 0; c < 4; ++c) {
    const float* src = qp + (size_t)irow * DH + c * 16 + hi * 8;
    qB[c] = pack8f(*(const float4*)src, *(const float4*)(src + 4));
  }

  // ---- mask pre-stage (whole 1024-k row of this b) ----
#pragma unroll
  for (int t2 = 0; t2 < 4; ++t2) {
    const int ix = tid + t2 * 256;
    mskf[ix] = mrow[ix] ? -INFINITY : 0.0f;
  }

  // ---- bias table: qR^T = pos . Q^T via MFMA; this wave: its qg rows,
  //      t-blocks tb = kh, kh+2, ... (5 of 10) ----
  for (int tb = kh; tb < 10; tb += 2) {
    int trow = tb * 32 + lo5; if (trow > 300) trow = 300;
    const float* pr = POS + (size_t)trow * DH;
    f32x16 z;
#pragma unroll
    for (int x = 0; x < 16; ++x) z[x] = 0.f;
#pragma unroll
    for (int c = 0; c < 4; ++c) {
      const float* s2 = pr + c * 16 + hi * 8;
      short8 af = pack8f(*(const float4*)s2, *(const float4*)(s2 + 4));
      z = __builtin_amdgcn_mfma_f32_32x32x16_bf16(af, qB[c], z, 0, 0, 0);
    }
#pragma unroll
    for (int rp = 0; rp < 8; ++rp) {
      const int r = rp * 2;
      int tp = KOFF(r) + 4 * hi + 32 * tb;
      if (tp < 306)  // keep junk cols inside the row (t<=300 ever read)
        *(unsigned*)(&qrs[qloc][tp]) = cvtpk(z[r], z[r + 1]);
    }
  }

  // ---- flash state (base-2 domain) ----
  const float SC = 0.18033688011112042f;  // 0.125 * log2(e)
  float m2 = -1e30f, lsum = 0.f;
  f32x16 acc0, acc1;
#pragma unroll
  for (int x = 0; x < 16; ++x) { acc0[x] = 0.f; acc1[x] = 0.f; }

  // ---- pipelined staging registers (T14) ----
  float4 kreg[2][4], vreg[2][4];
  auto LOADT = [&](int rdx) {
#pragma unroll
    for (int h = 0; h < 2; ++h) {
      const float* ksrc = kp + (size_t)(h * 512 + rdx * 64 + rK) * DH + q4 * 16;
#pragma unroll
      for (int i = 0; i < 4; ++i) kreg[h][i] = ((const float4*)ksrc)[i];
      const float* vsrc = vp + (size_t)(h * 512 + rdx * 64 + kkV) * DH + dwV * 16;
#pragma unroll
      for (int i = 0; i < 4; ++i) vreg[h][i] = ((const float4*)vsrc)[i];
    }
  };
  LOADT(0);

  for (int rd = 0; rd < 8; ++rd) {
    __syncthreads();  // prior round's ks/vt reads complete (covers table @rd=0)
    // ---- write staged regs -> LDS (bf16, swizzled) ----
#pragma unroll
    for (int h = 0; h < 2; ++h) {
      unsigned char* kb_ = kv + h * 8192;
      *(short8*)(kb_ + swz(rK, q4 * 32))      = pack8f(kreg[h][0], kreg[h][1]);
      *(short8*)(kb_ + swz(rK, q4 * 32 + 16)) = pack8f(kreg[h][2], kreg[h][3]);
      unsigned char* vb_ = kv + 16384 + h * 8192;
      const int db = dwV * 16, cb2 = kkV * 2;
      st_pair(vb_, db + 0,  cb2, vreg[h][0].x, vreg[h][0].y);
      st_pair(vb_, db + 2,  cb2, vreg[h][0].z, vreg[h][0].w);
      st_pair(vb_, db + 4,  cb2, vreg[h][1].x, vreg[h][1].y);
      st_pair(vb_, db + 6,  cb2, vreg[h][1].z, vreg[h][1].w);
      st_pair(vb_, db + 8,  cb2, vreg[h][2].x, vreg[h][2].y);
      st_pair(vb_, db + 10, cb2, vreg[h][2].z, vreg[h][2].w);
      st_pair(vb_, db + 12, cb2, vreg[h][3].x, vreg[h][3].y);
      st_pair(vb_, db + 14, cb2, vreg[h][3].z, vreg[h][3].w);
    }
    __syncthreads();
    if (rd < 7) LOADT(rd + 1);   // loads land during compute (T14)

    const int j0 = kh * 512 + rd * 64;

    // ---- S^T = K . Q^T ----
    f32x16 st[2];
#pragma unroll
    for (int kb = 0; kb < 2; ++kb) {
      f32x16 z;
#pragma unroll
      for (int x = 0; x < 16; ++x) z[x] = 0.f;
#pragma unroll
      for (int c = 0; c < 4; ++c) {
        short8 kf = *(const short8*)(ksh + swz(kb * 32 + lo5, c * 32 + hi * 16));
        z = __builtin_amdgcn_mfma_f32_32x32x16_bf16(kf, qB[c], z, 0, 0, 0);
      }
      st[kb] = z;
    }

    // ---- bias gather + scale + mask (lane owns q-row irow; k varies by reg) ----
#pragma unroll
    for (int kb = 0; kb < 2; ++kb) {
      const int jb = j0 + kb * 32;
      f32x4 mg[4];
#pragma unroll
      for (int g4 = 0; g4 < 4; ++g4)
        mg[g4] = *(const f32x4*)&mskf[jb + g4 * 8 + 4 * hi];
      const int relmin = jb - (i0 + qg * 32 + 31);
      const int relmax = jb + 31 - (i0 + qg * 32);
      if (relmin >= MAXL) {           // whole block saturates high -> idx 299
        const float bias = bf2f(qrs[qloc][299]);
#pragma unroll
        for (int r = 0; r < 16; ++r)
          st[kb][r] = (st[kb][r] + bias) * SC + mg[r >> 2][r & 3];
      } else if (relmax <= -MAXL) {   // saturates low -> wrap row 300
        const float bias = bf2f(qrs[qloc][300]);
#pragma unroll
        for (int r = 0; r < 16; ++r)
          st[kb][r] = (st[kb][r] + bias) * SC + mg[r >> 2][r & 3];
      } else {                        // near-diagonal: per-element gather
#pragma unroll
        for (int r = 0; r < 16; ++r) {
          const int rel = jb + KOFF(r) + 4 * hi - irow;
          const int idx = rel <= -MAXL ? 300 : (rel >= MAXL ? 299 : rel + MAXL - 1);
          st[kb][r] = (st[kb][r] + bf2f(qrs[qloc][idx])) * SC + mg[r >> 2][r & 3];
        }
      }
    }

    // ---- online softmax with defer-max (T13, base-2 THR=12) ----
    f32x16 mx;
#pragma unroll
    for (int r = 0; r < 16; ++r) mx[r] = fmaxf(st[0][r], st[1][r]);
#pragma unroll
    for (int w = 8; w > 0; w >>= 1)
#pragma unroll
      for (int r = 0; r < 8; ++r)
        if (r < w) mx[r] = fmaxf(mx[r], mx[r + w]);
    const float tmax = fmaxf(mx[0], __shfl_xor(mx[0], 32));
    if (!__all(tmax - m2 <= 12.0f)) {
      const float mnew = fmaxf(m2, tmax);
      const float alpha = exp2f(m2 - mnew);
      lsum *= alpha;
      acc0 *= alpha; acc1 *= alpha;
      m2 = mnew;
    }
#pragma unroll
    for (int kb = 0; kb < 2; ++kb)
#pragma unroll
      for (int r = 0; r < 16; ++r) st[kb][r] = exp2f(st[kb][r] - m2);
    f32x16 sx;
#pragma unroll
    for (int r = 0; r < 16; ++r) sx[r] = st[0][r] + st[1][r];
#pragma unroll
    for (int w = 8; w > 0; w >>= 1)
#pragma unroll
      for (int r = 0; r < 8; ++r)
        if (r < w) sx[r] = sx[r] + sx[r + w];
    lsum += sx[0] + __shfl_xor(sx[0], 32);

    // ---- P^T frags in-register: cvt_pk pairs, exchange +-32 via shfl_xor ----
    // (round-5-verified movement; only the pack op changed to cvtpk)
    short8 pf[4];
#pragma unroll
    for (int ch = 0; ch < 4; ++ch) {
      const int kb = ch >> 1, rb2 = (ch & 1) * 8;
      unsigned a  = cvtpk(st[kb][rb2 + 0], st[kb][rb2 + 1]);
      unsigned a2 = cvtpk(st[kb][rb2 + 2], st[kb][rb2 + 3]);
      unsigned bb = cvtpk(st[kb][rb2 + 4], st[kb][rb2 + 5]);
      unsigned b2 = cvtpk(st[kb][rb2 + 6], st[kb][rb2 + 7]);
      unsigned sa  = __shfl_xor(a, 32);
      unsigned sa2 = __shfl_xor(a2, 32);
      unsigned sbb = __shfl_xor(bb, 32);
      unsigned sb2 = __shfl_xor(b2, 32);
      U4S8 t;
      t.u[0] = hi ? sbb : a;    // k(0,1)  | k(8,9)
      t.u[1] = hi ? sb2 : a2;   // k(2,3)  | k(10,11)
      t.u[2] = hi ? bb  : sa;   // k(4,5)  | k(12,13)
      t.u[3] = hi ? b2  : sa2;  // k(6,7)  | k(14,15)
      pf[ch] = t.s;
    }

    // ---- PV: O^T += V^T . P^T ----
#pragma unroll
    for (int ch = 0; ch < 4; ++ch) {
      short8 vf0 = *(const short8*)(vth + swz(lo5,      ch * 32 + hi * 16));
      short8 vf1 = *(const short8*)(vth + swz(32 + lo5, ch * 32 + hi * 16));
      acc0 = __builtin_amdgcn_mfma_f32_32x32x16_bf16(vf0, pf[ch], acc0, 0, 0, 0);
      acc1 = __builtin_amdgcn_mfma_f32_32x32x16_bf16(vf1, pf[ch], acc1, 0, 0, 0);
    }
  }

  // ---- k-half merge (flash combine) + epilogue ----
  __syncthreads();
  float* mb = (float*)kv;  // reuse K/V LDS: 128 lanes * 37 f32 = 18944 B
  if (wave >= 2) {
    float* d = mb + ((wave - 2) * 64 + lane) * 37;
    d[0] = m2; d[1] = lsum;
#pragma unroll
    for (int r = 0; r < 16; ++r) { d[2 + r] = acc0[r]; d[18 + r] = acc1[r]; }
  }
  __syncthreads();
  if (wave < 2) {
    const float* d = mb + (wave * 64 + lane) * 37;
    const float m1 = d[0], l1 = d[1];
    const float mf = fmaxf(m2, m1);
    const float a0 = exp2f(m2 - mf), a1 = exp2f(m1 - mf);
    const float lf = lsum * a0 + l1 * a1;
    const float inv = 1.f / lf;
    float* op = OUT + bo + (size_t)irow * DH;
#pragma unroll
    for (int r = 0; r < 16; ++r) {
      const int d0 = KOFF(r) + 4 * hi;
      op[d0]      = (acc0[r] * a0 + d[2 + r]  * a1) * inv;
      op[d0 + 32] = (acc1[r] * a0 + d[18 + r] * a1) * inv;
    }
  }
}

extern "C" void kernel_launch(void* const* d_in, const int* in_sizes, int n_in,
                              void* d_out, int out_size, void* d_ws, size_t ws_size,
                              hipStream_t stream) {
  const float* q   = (const float*)d_in[0];
  const float* k   = (const float*)d_in[1];
  const float* v   = (const float*)d_in[2];
  const float* pos = (const float*)d_in[3];
  const int*   msk = (const int*)d_in[4];
  float* out = (float*)d_out;

  rp_attn32<<<dim3(1024), dim3(256), 0, stream>>>(q, k, v, pos, msk, out);
}